// Round 2
// baseline (1516.112 us; speedup 1.0000x reference)
//
#include <hip/hip_runtime.h>

#define NB 16
#define NT 2048
#define NC 512
#define NH 64
#define SCALE 0.125f

#define MT 64
#define NS 32
#define SM_STRIDE 98
#define SP_STRIDE 40

// ---------------- fused q/k/v projection ----------------
__global__ __launch_bounds__(256) void proj_kernel(
    const float* __restrict__ x, const float* __restrict__ Wq,
    const float* __restrict__ Wk, const float* __restrict__ Wv,
    float* __restrict__ q, float* __restrict__ k, float* __restrict__ v)
{
    __shared__ float xs[16 * NC];
    const int tid = threadIdx.x;
    const size_t rowBase = (size_t)blockIdx.x * 16;

    const float4* src = reinterpret_cast<const float4*>(x + rowBase * NC);
    float4* dst = reinterpret_cast<float4*>(xs);
#pragma unroll
    for (int i = 0; i < 8; ++i) dst[tid + 256 * i] = src[tid + 256 * i];
    __syncthreads();

    const int lane = tid & 63;
    const int w = tid >> 6;

    float aq[4] = {0.f, 0.f, 0.f, 0.f};
    float ak[4] = {0.f, 0.f, 0.f, 0.f};
    float av[4] = {0.f, 0.f, 0.f, 0.f};

#pragma unroll 2
    for (int c4 = 0; c4 < NC / 4; ++c4) {
        float4 xv[4];
#pragma unroll
        for (int rr = 0; rr < 4; ++rr)
            xv[rr] = *reinterpret_cast<const float4*>(&xs[(w * 4 + rr) * NC + c4 * 4]);
#pragma unroll
        for (int e = 0; e < 4; ++e) {
            const int c = c4 * 4 + e;
            const float wq = Wq[c * NH + lane];
            const float wk = Wk[c * NH + lane];
            const float wv = Wv[c * NH + lane];
#pragma unroll
            for (int rr = 0; rr < 4; ++rr) {
                const float xvv = reinterpret_cast<const float*>(&xv[rr])[e];
                aq[rr] = fmaf(xvv, wq, aq[rr]);
                ak[rr] = fmaf(xvv, wk, ak[rr]);
                av[rr] = fmaf(xvv, wv, av[rr]);
            }
        }
    }
#pragma unroll
    for (int rr = 0; rr < 4; ++rr) {
        const size_t row = rowBase + w * 4 + rr;
        q[row * NH + lane] = aq[rr];
        k[row * NH + lane] = ak[rr];
        v[row * NH + lane] = av[rr];
    }
}

// ---------------- fused rel-attention (flash-style) ----------------
// Per (t,s), s<=t:  att = qk*SCALE + R where
//   R = q[t].Er[T-1]      if t==s
//   R = 0                 if t==s+1
//   R = q[s+1].Er[t-s-2]  if t>=s+2
__global__ __launch_bounds__(256) void attn_kernel(
    const float* __restrict__ q, const float* __restrict__ k,
    const float* __restrict__ v, const float* __restrict__ Er,
    float* __restrict__ out)
{
    __shared__ float sM[NS * SM_STRIDE];   // rel GEMM tile: M[a][u]
    __shared__ float sP[MT * SP_STRIDE];   // probabilities tile
    __shared__ float sDiag[MT];            // q[t].Er[T-1]

    const int tid = threadIdx.x;
    const int jj = tid & 7;        // ds/h quad index (0..7)
    const int ii = tid >> 3;       // 0..31

    // work-balance swizzle: pair tile tq with 31-tq across grid halves
    const int lin  = blockIdx.y * gridDim.x + blockIdx.x;  // 0..511
    const int half = lin >> 8;
    const int idx  = lin & 255;
    const int bb   = idx >> 4;                 // batch 0..15
    int tq = idx & 15;
    if (half) tq = 31 - tq;
    const int t0 = tq * MT;

    const size_t bOff = (size_t)bb * NT * NH;
    const float* qb = q + bOff;
    const float* kb = k + bOff;
    const float* vb = v + bOff;

    if (tid < MT) {
        const float* qr = qb + (size_t)(t0 + tid) * NH;
        const float* er = Er + (size_t)(NT - 1) * NH;
        float s = 0.f;
#pragma unroll 8
        for (int h = 0; h < NH; ++h) s = fmaf(qr[h], er[h], s);
        sDiag[tid] = s;
    }
    __syncthreads();

    float m[2] = {-1e30f, -1e30f};
    float l[2] = {0.f, 0.f};
    float O[2][2][4];
#pragma unroll
    for (int kk = 0; kk < 2; ++kk)
#pragma unroll
        for (int hh = 0; hh < 2; ++hh)
#pragma unroll
            for (int c = 0; c < 4; ++c) O[kk][hh][c] = 0.f;

    const float* qp0 = qb + (size_t)(t0 + ii) * NH;
    const float* qp1 = qb + (size_t)(t0 + ii + 32) * NH;

    for (int s0 = 0; s0 < t0 + MT; s0 += NS) {
        // ---- QK^T ----
        float qk[2][4];
#pragma unroll
        for (int kk = 0; kk < 2; ++kk)
#pragma unroll
            for (int dq = 0; dq < 4; ++dq) qk[kk][dq] = 0.f;

        const float* kp[4];
#pragma unroll
        for (int dq = 0; dq < 4; ++dq)
            kp[dq] = kb + (size_t)(s0 + 4 * jj + dq) * NH;

#pragma unroll 2
        for (int h4 = 0; h4 < 16; ++h4) {
            const float4 qv0 = *reinterpret_cast<const float4*>(qp0 + 4 * h4);
            const float4 qv1 = *reinterpret_cast<const float4*>(qp1 + 4 * h4);
            float4 kv[4];
#pragma unroll
            for (int dq = 0; dq < 4; ++dq)
                kv[dq] = *reinterpret_cast<const float4*>(kp[dq] + 4 * h4);
#pragma unroll
            for (int dq = 0; dq < 4; ++dq)
#pragma unroll
                for (int e = 0; e < 4; ++e) {
                    const float ke = reinterpret_cast<const float*>(&kv[dq])[e];
                    qk[0][dq] = fmaf(reinterpret_cast<const float*>(&qv0)[e], ke, qk[0][dq]);
                    qk[1][dq] = fmaf(reinterpret_cast<const float*>(&qv1)[e], ke, qk[1][dq]);
                }
        }

        // ---- rel GEMM: M[a][u] = q[s0+1+a] . Er[rbase+u] ----
        const int rbase = t0 - s0 - 33;
        float Mreg[3][4];
#pragma unroll
        for (int uu = 0; uu < 3; ++uu)
#pragma unroll
            for (int dq = 0; dq < 4; ++dq) Mreg[uu][dq] = 0.f;

        const float* ap[4];
#pragma unroll
        for (int dq = 0; dq < 4; ++dq) {
            int ar = s0 + 1 + 4 * jj + dq;
            if (ar > NT - 1) ar = NT - 1;   // clamped rows are never consumed
            ap[dq] = qb + (size_t)ar * NH;
        }
        const float* ep[3];
#pragma unroll
        for (int uu = 0; uu < 3; ++uu) {
            int r = rbase + ii + 32 * uu;
            if (r < 0) r = 0;               // clamped rows are never consumed
            ep[uu] = Er + (size_t)r * NH;
        }

#pragma unroll 2
        for (int h4 = 0; h4 < 16; ++h4) {
            float4 ev[3];
#pragma unroll
            for (int uu = 0; uu < 3; ++uu)
                ev[uu] = *reinterpret_cast<const float4*>(ep[uu] + 4 * h4);
            float4 av4[4];
#pragma unroll
            for (int dq = 0; dq < 4; ++dq)
                av4[dq] = *reinterpret_cast<const float4*>(ap[dq] + 4 * h4);
#pragma unroll
            for (int uu = 0; uu < 3; ++uu)
#pragma unroll
                for (int dq = 0; dq < 4; ++dq)
#pragma unroll
                    for (int e = 0; e < 4; ++e)
                        Mreg[uu][dq] = fmaf(reinterpret_cast<const float*>(&av4[dq])[e],
                                            reinterpret_cast<const float*>(&ev[uu])[e],
                                            Mreg[uu][dq]);
        }
#pragma unroll
        for (int uu = 0; uu < 3; ++uu)
#pragma unroll
            for (int dq = 0; dq < 4; ++dq)
                sM[(4 * jj + dq) * SM_STRIDE + (ii + 32 * uu)] = Mreg[uu][dq];

        __syncthreads();  // sM ready; also guarantees prev-iter PV done with sP

        // ---- assemble scores + online softmax ----
        float p[2][4];
#pragma unroll
        for (int kk = 0; kk < 2; ++kk) {
            const int dt = ii + 32 * kk;
            const int t = t0 + dt;
            float mx = -1e30f;
#pragma unroll
            for (int dq = 0; dq < 4; ++dq) {
                const int ds = 4 * jj + dq;
                const int s = s0 + ds;
                float sc = -1e30f;
                if (s <= t) {
                    sc = qk[kk][dq] * SCALE;
                    const int d = t - s;
                    if (d == 0) sc += sDiag[dt];
                    else if (d >= 2) sc += sM[ds * SM_STRIDE + (dt - ds + 31)];
                }
                p[kk][dq] = sc;
                mx = fmaxf(mx, sc);
            }
            mx = fmaxf(mx, __shfl_xor(mx, 1));
            mx = fmaxf(mx, __shfl_xor(mx, 2));
            mx = fmaxf(mx, __shfl_xor(mx, 4));
            const float mn = fmaxf(m[kk], mx);
            const float fac = __expf(m[kk] - mn);
            float sum = 0.f;
#pragma unroll
            for (int dq = 0; dq < 4; ++dq) {
                const float pv = __expf(p[kk][dq] - mn);
                p[kk][dq] = pv;
                sum += pv;
            }
            sum += __shfl_xor(sum, 1);
            sum += __shfl_xor(sum, 2);
            sum += __shfl_xor(sum, 4);
            l[kk] = l[kk] * fac + sum;
            m[kk] = mn;
#pragma unroll
            for (int hh = 0; hh < 2; ++hh)
#pragma unroll
                for (int c = 0; c < 4; ++c) O[kk][hh][c] *= fac;
            float4 p4;
#pragma unroll
            for (int dq = 0; dq < 4; ++dq)
                reinterpret_cast<float*>(&p4)[dq] = p[kk][dq];
            *reinterpret_cast<float4*>(&sP[dt * SP_STRIDE + 4 * jj]) = p4;
        }
        __syncthreads();  // sP ready

        // ---- PV ----
#pragma unroll 2
        for (int ds4 = 0; ds4 < 8; ++ds4) {
            const float4 pr0 = *reinterpret_cast<const float4*>(&sP[ii * SP_STRIDE + 4 * ds4]);
            const float4 pr1 = *reinterpret_cast<const float4*>(&sP[(ii + 32) * SP_STRIDE + 4 * ds4]);
#pragma unroll
            for (int e2 = 0; e2 < 4; ++e2) {
                const float* vrow = vb + (size_t)(s0 + 4 * ds4 + e2) * NH;
                const float4 vv0 = *reinterpret_cast<const float4*>(vrow + 4 * jj);
                const float4 vv1 = *reinterpret_cast<const float4*>(vrow + 4 * jj + 32);
                const float pw0 = reinterpret_cast<const float*>(&pr0)[e2];
                const float pw1 = reinterpret_cast<const float*>(&pr1)[e2];
#pragma unroll
                for (int c = 0; c < 4; ++c) {
                    const float v0 = reinterpret_cast<const float*>(&vv0)[c];
                    const float v1 = reinterpret_cast<const float*>(&vv1)[c];
                    O[0][0][c] = fmaf(pw0, v0, O[0][0][c]);
                    O[0][1][c] = fmaf(pw0, v1, O[0][1][c]);
                    O[1][0][c] = fmaf(pw1, v0, O[1][0][c]);
                    O[1][1][c] = fmaf(pw1, v1, O[1][1][c]);
                }
            }
        }
    }

    // ---- final normalize + store ----
#pragma unroll
    for (int kk = 0; kk < 2; ++kk) {
        const float inv = 1.f / l[kk];
        float* orow = out + bOff + (size_t)(t0 + ii + 32 * kk) * NH;
#pragma unroll
        for (int hh = 0; hh < 2; ++hh) {
            float4 o4;
#pragma unroll
            for (int c = 0; c < 4; ++c)
                reinterpret_cast<float*>(&o4)[c] = O[kk][hh][c] * inv;
            *reinterpret_cast<float4*>(orow + 4 * jj + 32 * hh) = o4;
        }
    }
}

extern "C" void kernel_launch(void* const* d_in, const int* in_sizes, int n_in,
                              void* d_out, int out_size, void* d_ws, size_t ws_size,
                              hipStream_t stream) {
    (void)in_sizes; (void)n_in; (void)out_size; (void)ws_size;
    const float* x  = (const float*)d_in[0];
    const float* Wq = (const float*)d_in[1];
    const float* Wk = (const float*)d_in[2];
    const float* Wv = (const float*)d_in[3];
    const float* Er = (const float*)d_in[4];
    float* outp = (float*)d_out;

    float* ws = (float*)d_ws;
    const size_t BTH = (size_t)NB * NT * NH;   // 2,097,152
    float* qv = ws;
    float* kv = ws + BTH;
    float* vv = ws + 2 * BTH;                  // total 24 MB of d_ws

    proj_kernel<<<dim3(NB * NT / 16), dim3(256), 0, stream>>>(x, Wq, Wk, Wv, qv, kv, vv);
    attn_kernel<<<dim3(NT / MT, NB), dim3(256), 0, stream>>>(qv, kv, vv, Er, outp);
}

// Round 3
// 402.890 us; speedup vs baseline: 3.7631x; 3.7631x over previous
//
#include <hip/hip_runtime.h>

#define NB 16
#define NT 2048
#define NC 512
#define NH 64
#define SCALE 0.125f

typedef __attribute__((ext_vector_type(8))) short bf16x8;
typedef __attribute__((ext_vector_type(16))) float f32x16;
typedef __attribute__((ext_vector_type(4))) unsigned int u32x4;

__device__ __forceinline__ unsigned short f2b(float f) {
    unsigned u = __builtin_bit_cast(unsigned, f);
    u = (u + 0x7fffu + ((u >> 16) & 1u)) >> 16;   // RNE
    return (unsigned short)u;
}
__device__ __forceinline__ float b2f(unsigned short s) {
    return __builtin_bit_cast(float, (unsigned)s << 16);
}
#define MFMA32(a, b, c) __builtin_amdgcn_mfma_f32_32x32x16_bf16((a), (b), (c), 0, 0, 0)
#define LD8(p) (*reinterpret_cast<const bf16x8*>(p))

// ---------------- fused q/k/v projection (f32 math, bf16 out, V transposed) ----------------
__global__ __launch_bounds__(256) void proj_kernel(
    const float* __restrict__ x, const float* __restrict__ Wq,
    const float* __restrict__ Wk, const float* __restrict__ Wv,
    unsigned short* __restrict__ qb, unsigned short* __restrict__ kb,
    unsigned short* __restrict__ vtg)
{
    __shared__ float xs[16 * NC];
    __shared__ unsigned short vtile[64 * 20];   // [h][row16], stride 20 for bank spread + 8B align
    const int tid = threadIdx.x;
    const size_t rowBase = (size_t)blockIdx.x * 16;

    const float4* src = reinterpret_cast<const float4*>(x + rowBase * NC);
    float4* dst = reinterpret_cast<float4*>(xs);
#pragma unroll
    for (int i = 0; i < 8; ++i) dst[tid + 256 * i] = src[tid + 256 * i];
    __syncthreads();

    const int lane = tid & 63;
    const int w = tid >> 6;

    float aq[4] = {0.f, 0.f, 0.f, 0.f};
    float ak[4] = {0.f, 0.f, 0.f, 0.f};
    float av[4] = {0.f, 0.f, 0.f, 0.f};

#pragma unroll 2
    for (int c4 = 0; c4 < NC / 4; ++c4) {
        float4 xv[4];
#pragma unroll
        for (int rr = 0; rr < 4; ++rr)
            xv[rr] = *reinterpret_cast<const float4*>(&xs[(w * 4 + rr) * NC + c4 * 4]);
#pragma unroll
        for (int e = 0; e < 4; ++e) {
            const int c = c4 * 4 + e;
            const float wq = Wq[c * NH + lane];
            const float wk = Wk[c * NH + lane];
            const float wv = Wv[c * NH + lane];
#pragma unroll
            for (int rr = 0; rr < 4; ++rr) {
                const float xvv = reinterpret_cast<const float*>(&xv[rr])[e];
                aq[rr] = fmaf(xvv, wq, aq[rr]);
                ak[rr] = fmaf(xvv, wk, ak[rr]);
                av[rr] = fmaf(xvv, wv, av[rr]);
            }
        }
    }
#pragma unroll
    for (int rr = 0; rr < 4; ++rr) {
        const size_t row = rowBase + w * 4 + rr;
        qb[row * NH + lane] = f2b(aq[rr]);
        kb[row * NH + lane] = f2b(ak[rr]);
        vtile[lane * 20 + (w * 4 + rr)] = f2b(av[rr]);
    }
    __syncthreads();
    // transposed store of V: vtg[b][h][t]
    const int h = tid >> 2, c4o = tid & 3;
    ushort4 vv = *reinterpret_cast<const ushort4*>(&vtile[h * 20 + c4o * 4]);
    const size_t bidx = rowBase >> 11;
    const size_t tloc = rowBase & 2047;
    *reinterpret_cast<ushort4*>(vtg + (bidx * NH + h) * NT + tloc + c4o * 4) = vv;
}

// ---------------- Er f32 -> bf16 ----------------
__global__ __launch_bounds__(256) void er_cast(const float* __restrict__ er,
                                               unsigned short* __restrict__ erb)
{
    const int i = (blockIdx.x * 256 + threadIdx.x) * 4;
    float4 v = *reinterpret_cast<const float4*>(er + i);
    ushort4 o = make_ushort4(f2b(v.x), f2b(v.y), f2b(v.z), f2b(v.w));
    *reinterpret_cast<ushort4*>(erb + i) = o;
}

// ---------------- MFMA rel-attention, 1 wave / 32 q-rows, no barriers ----------------
// score(t,s) = qk*SCALE + { diag[t] if t==s ; 0 if t==s+1 ; q[s+1].Er[t-s-2] if t>=s+2 }
__global__ __launch_bounds__(64) void attn_mfma(
    const unsigned short* __restrict__ qb, const unsigned short* __restrict__ kb,
    const unsigned short* __restrict__ vt, const unsigned short* __restrict__ erb,
    float* __restrict__ out)
{
    __shared__ float sM[32 * 64];   // rel tile M'[da][du], 8 KB

    const int l  = threadIdx.x;
    const int r  = l & 31;     // this lane's q-row within the tile (lane-local!)
    const int h5 = l >> 5;

    // balance swizzle: pair tq with 63-tq across grid halves
    const int lin = blockIdx.x;
    const int half = lin >> 9;
    const int idx  = lin & 511;
    const int bb   = idx >> 5;
    const int tqi  = idx & 31;
    const int tq   = half ? (63 - tqi) : tqi;
    const int t0   = tq * 32;

    const unsigned short* qB  = qb  + (size_t)bb * NT * NH;
    const unsigned short* kB  = kb  + (size_t)bb * NT * NH;
    const unsigned short* vtB = vt  + (size_t)bb * NH * NT;

    // Q fragments (B-operand layout: lane holds q-row r, h-chunk 16ks+8*h5+j)
    const unsigned short* qp = qB + (size_t)(t0 + r) * NH + h5 * 8;
    bf16x8 qf[4];
#pragma unroll
    for (int ks = 0; ks < 4; ++ks) qf[ks] = LD8(qp + ks * 16);

    // diag[r] = q[t0+r] . Er[T-1]  (lane-local)
    float diag = 0.f;
    {
        const unsigned short* qrow = qB + (size_t)(t0 + r) * NH;
        const unsigned short* el   = erb + (size_t)(NT - 1) * NH;
#pragma unroll 8
        for (int h = 0; h < NH; ++h) diag += b2f(qrow[h]) * b2f(el[h]);
    }

    float mrun = -1e30f, lrun = 0.f;
    f32x16 o0 = {};   // O^T accum, h-tile 0 (h 0..31)
    f32x16 o1 = {};   // h-tile 1 (h 32..63)

    for (int s0 = 0; s0 <= t0; s0 += 32) {
        const int D0 = t0 - s0;

        // ---- rel GEMM: M'[da][du] = q[s0+1+da] . Er[D0-33+du] ----
        f32x16 mA = {}, mB = {};
        {
            int arow = s0 + 1 + r; if (arow > NT - 1) arow = NT - 1;          // clamped rows unused
            int e0 = D0 - 33 + r;       const int e0c = e0 < 0 ? 0 : e0;      // clamped rows unused
            int e1 = e0 + 32;           const int e1c = e1 < 0 ? 0 : e1;
            const unsigned short* ap  = qB  + (size_t)arow * NH + h5 * 8;
            const unsigned short* ep0 = erb + (size_t)e0c  * NH + h5 * 8;
            const unsigned short* ep1 = erb + (size_t)e1c  * NH + h5 * 8;
#pragma unroll
            for (int ks = 0; ks < 4; ++ks) {
                bf16x8 af = LD8(ap + ks * 16);
                mA = MFMA32(af, LD8(ep0 + ks * 16), mA);
                mB = MFMA32(af, LD8(ep1 + ks * 16), mB);
            }
        }
#pragma unroll
        for (int reg = 0; reg < 16; ++reg) {
            const int da = (reg & 3) + 8 * (reg >> 2) + 4 * h5;
            sM[da * 64 + r]      = mA[reg];
            sM[da * 64 + r + 32] = mB[reg];
        }

        // ---- S^T = K . Q^T : lane holds row r, keys dc in regs ----
        f32x16 st = {};
        {
            const unsigned short* kp = kB + (size_t)(s0 + r) * NH + h5 * 8;
#pragma unroll
            for (int ks = 0; ks < 4; ++ks)
                st = MFMA32(LD8(kp + ks * 16), qf[ks], st);
        }

        // ---- assemble scores + online softmax (row r is lane-local) ----
        float p[16];
        float mx = -1e30f;
#pragma unroll
        for (int reg = 0; reg < 16; ++reg) {
            const int dc = (reg & 3) + 8 * (reg >> 2) + 4 * h5;
            const int d  = r - dc + D0;
            float sc = st[reg] * SCALE;
            const float Mv = sM[dc * 64 + (r - dc + 31)];   // Er row = d-2  (verified algebra)
            sc += (d >= 2) ? Mv : ((d == 0) ? diag : 0.0f);
            sc = (d < 0) ? -1e30f : sc;
            p[reg] = sc;
            mx = fmaxf(mx, sc);
        }
        mx = fmaxf(mx, __shfl_xor(mx, 32));
        const float mn  = fmaxf(mrun, mx);
        const float fac = __expf(mrun - mn);
        float sum = 0.f;
#pragma unroll
        for (int reg = 0; reg < 16; ++reg) {
            const float pv = __expf(p[reg] - mn);
            p[reg] = pv;
            sum += pv;
        }
        sum += __shfl_xor(sum, 32);
        lrun = lrun * fac + sum;
        mrun = mn;
        o0 *= fac;
        o1 *= fac;

        // ---- P -> bf16 A/B-frag relayout (pack + cross-half shfl) ----
        unsigned c[8];
#pragma unroll
        for (int i = 0; i < 8; ++i)
            c[i] = (unsigned)f2b(p[2 * i]) | ((unsigned)f2b(p[2 * i + 1]) << 16);
        unsigned w0, w1, w2, w3, w4, w5, w6, w7;
        {
            const unsigned s0w = (unsigned)__shfl_xor((int)c[0], 32);
            const unsigned s1w = (unsigned)__shfl_xor((int)c[1], 32);
            const unsigned s2w = (unsigned)__shfl_xor((int)c[2], 32);
            const unsigned s3w = (unsigned)__shfl_xor((int)c[3], 32);
            w0 = h5 ? s2w : c[0];   w2 = h5 ? c[2] : s0w;
            w1 = h5 ? s3w : c[1];   w3 = h5 ? c[3] : s1w;
            const unsigned s4w = (unsigned)__shfl_xor((int)c[4], 32);
            const unsigned s5w = (unsigned)__shfl_xor((int)c[5], 32);
            const unsigned s6w = (unsigned)__shfl_xor((int)c[6], 32);
            const unsigned s7w = (unsigned)__shfl_xor((int)c[7], 32);
            w4 = h5 ? s6w : c[4];   w6 = h5 ? c[6] : s4w;
            w5 = h5 ? s7w : c[5];   w7 = h5 ? c[7] : s5w;
        }
        u32x4 pa = {w0, w1, w2, w3};
        u32x4 pb = {w4, w5, w6, w7};
        const bf16x8 pf0 = __builtin_bit_cast(bf16x8, pa);   // keys s0+0..15
        const bf16x8 pf1 = __builtin_bit_cast(bf16x8, pb);   // keys s0+16..31

        // ---- PV: O^T = V^T . P  (A = V^T rows h=lane&31, B = P) ----
        {
            const unsigned short* vp0 = vtB + (size_t)r        * NT + s0 + h5 * 8;
            const unsigned short* vp1 = vtB + (size_t)(r + 32) * NT + s0 + h5 * 8;
            o0 = MFMA32(LD8(vp0),      pf0, o0);
            o0 = MFMA32(LD8(vp0 + 16), pf1, o0);
            o1 = MFMA32(LD8(vp1),      pf0, o1);
            o1 = MFMA32(LD8(vp1 + 16), pf1, o1);
        }
    }

    // ---- normalize + store: lane holds row r, h = (reg&3)+8*(reg>>2)+4*h5 (+32 for o1) ----
    const float inv = 1.f / lrun;
    float* ob = out + (size_t)bb * NT * NH + (size_t)(t0 + r) * NH;
#pragma unroll
    for (int g = 0; g < 4; ++g) {
        float4 v0, v1;
        v0.x = o0[4 * g + 0] * inv; v0.y = o0[4 * g + 1] * inv;
        v0.z = o0[4 * g + 2] * inv; v0.w = o0[4 * g + 3] * inv;
        v1.x = o1[4 * g + 0] * inv; v1.y = o1[4 * g + 1] * inv;
        v1.z = o1[4 * g + 2] * inv; v1.w = o1[4 * g + 3] * inv;
        *reinterpret_cast<float4*>(ob + 8 * g + 4 * h5)      = v0;
        *reinterpret_cast<float4*>(ob + 32 + 8 * g + 4 * h5) = v1;
    }
}

extern "C" void kernel_launch(void* const* d_in, const int* in_sizes, int n_in,
                              void* d_out, int out_size, void* d_ws, size_t ws_size,
                              hipStream_t stream) {
    (void)in_sizes; (void)n_in; (void)out_size; (void)ws_size;
    const float* x  = (const float*)d_in[0];
    const float* Wq = (const float*)d_in[1];
    const float* Wk = (const float*)d_in[2];
    const float* Wv = (const float*)d_in[3];
    const float* Er = (const float*)d_in[4];
    float* outp = (float*)d_out;

    const size_t BTH = (size_t)NB * NT * NH;          // 2,097,152
    unsigned short* qbp = (unsigned short*)d_ws;
    unsigned short* kbp = qbp + BTH;
    unsigned short* vtp = kbp + BTH;
    unsigned short* erp = vtp + BTH;                  // + 256 KB  (total ~12.25 MB)

    proj_kernel<<<dim3(NB * NT / 16), dim3(256), 0, stream>>>(x, Wq, Wk, Wv, qbp, kbp, vtp);
    er_cast<<<dim3(NT * NH / 1024), dim3(256), 0, stream>>>(Er, erp);
    attn_mfma<<<dim3(NB * (NT / 32)), dim3(64), 0, stream>>>(qbp, kbp, vtp, erp, outp);
}

// Round 4
// 263.804 us; speedup vs baseline: 5.7471x; 1.5272x over previous
//
#include <hip/hip_runtime.h>

#define NB 16
#define NT 2048
#define NC 512
#define NH 64
#define SCALE 0.125f

typedef __attribute__((ext_vector_type(8))) short bf16x8;
typedef __attribute__((ext_vector_type(16))) float f32x16;
typedef __attribute__((ext_vector_type(4))) unsigned int u32x4;
typedef __attribute__((ext_vector_type(8))) unsigned short u16x8;

__device__ __forceinline__ unsigned short f2b(float f) {
    unsigned u = __builtin_bit_cast(unsigned, f);
    u = (u + 0x7fffu + ((u >> 16) & 1u)) >> 16;   // RNE
    return (unsigned short)u;
}
__device__ __forceinline__ float b2f(unsigned short s) {
    return __builtin_bit_cast(float, (unsigned)s << 16);
}
#define MFMA32(a, b, c) __builtin_amdgcn_mfma_f32_32x32x16_bf16((a), (b), (c), 0, 0, 0)
#define LD8(p) (*reinterpret_cast<const bf16x8*>(p))

// ---------------- W -> Wt[192][512] bf16 (row = output col, col = k) ----------------
__global__ __launch_bounds__(256) void wcast(
    const float* __restrict__ Wq, const float* __restrict__ Wk,
    const float* __restrict__ Wv, unsigned short* __restrict__ wt)
{
    const int tid = blockIdx.x * 256 + threadIdx.x;   // 0..12287
    const int ng = tid >> 6;                           // 0..191
    const int k8 = tid & 63;                           // 0..63
    const float* W = (ng < 64) ? Wq : (ng < 128 ? Wk : Wv);
    const int n = ng & 63;
    u16x8 o;
#pragma unroll
    for (int i = 0; i < 8; ++i) o[i] = f2b(W[(k8 * 8 + i) * NH + n]);
    *reinterpret_cast<u16x8*>(wt + (size_t)ng * NC + k8 * 8) = o;
}

// ---------------- Er f32 -> bf16 ----------------
__global__ __launch_bounds__(256) void er_cast(const float* __restrict__ er,
                                               unsigned short* __restrict__ erb)
{
    const int i = (blockIdx.x * 256 + threadIdx.x) * 4;
    float4 v = *reinterpret_cast<const float4*>(er + i);
    ushort4 o = make_ushort4(f2b(v.x), f2b(v.y), f2b(v.z), f2b(v.w));
    *reinterpret_cast<ushort4*>(erb + i) = o;
}

// ---------------- MFMA projection: 1 wave / 32 rows, q,k row-major + V^T ----------------
__global__ __launch_bounds__(64) void proj_mfma(
    const float* __restrict__ x, const unsigned short* __restrict__ wt,
    unsigned short* __restrict__ qb, unsigned short* __restrict__ kb,
    unsigned short* __restrict__ vtg)
{
    const int l = threadIdx.x;
    const int r = l & 31;
    const int h5 = l >> 5;
    const size_t t0 = (size_t)blockIdx.x * 32;
    const float* xr = x + (t0 + r) * NC + 8 * h5;

    f32x16 a0 = {}, a1 = {}, a2 = {}, a3 = {}, a4 = {}, a5 = {};

#pragma unroll
    for (int ks = 0; ks < 32; ++ks) {
        const int k0 = ks * 16;
        const float4 xlo = *reinterpret_cast<const float4*>(xr + k0);
        const float4 xhi = *reinterpret_cast<const float4*>(xr + k0 + 4);
        u32x4 aw;
        aw[0] = (unsigned)f2b(xlo.x) | ((unsigned)f2b(xlo.y) << 16);
        aw[1] = (unsigned)f2b(xlo.z) | ((unsigned)f2b(xlo.w) << 16);
        aw[2] = (unsigned)f2b(xhi.x) | ((unsigned)f2b(xhi.y) << 16);
        aw[3] = (unsigned)f2b(xhi.z) | ((unsigned)f2b(xhi.w) << 16);
        const bf16x8 af = __builtin_bit_cast(bf16x8, aw);
        const unsigned short* wp = wt + (size_t)r * NC + k0 + 8 * h5;
        a0 = MFMA32(af, LD8(wp),            a0);
        a1 = MFMA32(af, LD8(wp + 32 * NC),  a1);
        a2 = MFMA32(af, LD8(wp + 64 * NC),  a2);
        a3 = MFMA32(af, LD8(wp + 96 * NC),  a3);
        a4 = MFMA32(af, LD8(wp + 128 * NC), a4);
        a5 = MFMA32(af, LD8(wp + 160 * NC), a5);
    }

    // q,k row-major stores (lane -> col, reg -> row)
#pragma unroll
    for (int reg = 0; reg < 16; ++reg) {
        const int tr = (reg & 3) + 8 * (reg >> 2) + 4 * h5;
        const size_t row = t0 + tr;
        qb[row * NH + r]      = f2b(a0[reg]);
        qb[row * NH + 32 + r] = f2b(a1[reg]);
        kb[row * NH + r]      = f2b(a2[reg]);
        kb[row * NH + 32 + r] = f2b(a3[reg]);
    }
    // V^T stores, 4 consecutive t packed per store
    const size_t bidx = t0 >> 11;
    const int tl0 = (int)(t0 & 2047);
#pragma unroll
    for (int g = 0; g < 4; ++g) {
        ushort4 p0, p1;
        p0.x = f2b(a4[4 * g + 0]); p0.y = f2b(a4[4 * g + 1]);
        p0.z = f2b(a4[4 * g + 2]); p0.w = f2b(a4[4 * g + 3]);
        p1.x = f2b(a5[4 * g + 0]); p1.y = f2b(a5[4 * g + 1]);
        p1.z = f2b(a5[4 * g + 2]); p1.w = f2b(a5[4 * g + 3]);
        const int tb = tl0 + 8 * g + 4 * h5;
        *reinterpret_cast<ushort4*>(vtg + (bidx * NH + r)      * NT + tb) = p0;
        *reinterpret_cast<ushort4*>(vtg + (bidx * NH + 32 + r) * NT + tb) = p1;
    }
}

// ---------------- MFMA rel-attention, 4 waves split-K per q-tile ----------------
// score(t,s) = qk*SCALE + { diag[t] if t==s ; 0 if t==s+1 ; q[s+1].Er[t-s-2] if t>=s+2 }
__global__ __launch_bounds__(256) void attn_mfma(
    const unsigned short* __restrict__ qb, const unsigned short* __restrict__ kb,
    const unsigned short* __restrict__ vt, const unsigned short* __restrict__ erb,
    float* __restrict__ out)
{
    __shared__ float lds[4 * 2048];   // 32 KB: per-wave sM during loop; combine buffer after

    const int tid = threadIdx.x;
    const int l  = tid & 63;
    const int w  = tid >> 6;
    const int r  = l & 31;
    const int h5 = (l >> 5) & 1;

    // balance swizzle: pair tq with 63-tq across grid halves
    const int lin  = blockIdx.x;
    const int half = lin >> 9;
    const int idx  = lin & 511;
    const int bb   = idx >> 5;
    const int tqi  = idx & 31;
    const int tq   = half ? (63 - tqi) : tqi;
    const int t0   = tq * 32;

    const unsigned short* qB  = qb + (size_t)bb * NT * NH;
    const unsigned short* kB  = kb + (size_t)bb * NT * NH;
    const unsigned short* vtB = vt + (size_t)bb * NH * NT;

    float* sM = lds + w * 2048;

    // Q fragments (B-operand: lane holds q-row r)
    const unsigned short* qp = qB + (size_t)(t0 + r) * NH + h5 * 8;
    bf16x8 qf[4];
#pragma unroll
    for (int ks = 0; ks < 4; ++ks) qf[ks] = LD8(qp + ks * 16);

    // diag[r] = q[t0+r] . Er[T-1]
    float diag = 0.f;
    {
        const unsigned short* qrow = qB + (size_t)(t0 + r) * NH;
        const unsigned short* el   = erb + (size_t)(NT - 1) * NH;
#pragma unroll 8
        for (int h = 0; h < NH; ++h) diag += b2f(qrow[h]) * b2f(el[h]);
    }

    float mrun = -1e30f, lrun = 0.f;
    f32x16 o0 = {}, o1 = {};

    const int ntiles = tq + 1;
    for (int it = w; it < ntiles; it += 4) {
        const int s0 = it * 32;
        const int D0 = t0 - s0;

        // ---- rel GEMM: M'[da][du] = q[s0+1+da] . Er[D0-33+du] ----
        f32x16 mA = {}, mB = {};
        {
            int arow = s0 + 1 + r; if (arow > NT - 1) arow = NT - 1;       // clamped rows unused
            int e0 = D0 - 33 + r;  const int e0c = e0 < 0 ? 0 : e0;        // clamped rows unused
            int e1 = e0 + 32;      const int e1c = e1 < 0 ? 0 : e1;
            const unsigned short* ap  = qB  + (size_t)arow * NH + h5 * 8;
            const unsigned short* ep0 = erb + (size_t)e0c  * NH + h5 * 8;
            const unsigned short* ep1 = erb + (size_t)e1c  * NH + h5 * 8;
#pragma unroll
            for (int ks = 0; ks < 4; ++ks) {
                bf16x8 af = LD8(ap + ks * 16);
                mA = MFMA32(af, LD8(ep0 + ks * 16), mA);
                mB = MFMA32(af, LD8(ep1 + ks * 16), mB);
            }
        }
#pragma unroll
        for (int reg = 0; reg < 16; ++reg) {
            const int da = (reg & 3) + 8 * (reg >> 2) + 4 * h5;
            sM[da * 64 + r]      = mA[reg];
            sM[da * 64 + r + 32] = mB[reg];
        }

        // ---- S^T = K . Q^T ----
        f32x16 st = {};
        {
            const unsigned short* kp = kB + (size_t)(s0 + r) * NH + h5 * 8;
#pragma unroll
            for (int ks = 0; ks < 4; ++ks)
                st = MFMA32(LD8(kp + ks * 16), qf[ks], st);
        }

        // ---- scores + online softmax (row r lane-local) ----
        float p[16];
        float mx = -1e30f;
#pragma unroll
        for (int reg = 0; reg < 16; ++reg) {
            const int dc = (reg & 3) + 8 * (reg >> 2) + 4 * h5;
            const int d  = r - dc + D0;
            float sc = st[reg] * SCALE;
            const float Mv = sM[dc * 64 + (r - dc + 31)];
            sc += (d >= 2) ? Mv : ((d == 0) ? diag : 0.0f);
            sc = (d < 0) ? -1e30f : sc;
            p[reg] = sc;
            mx = fmaxf(mx, sc);
        }
        mx = fmaxf(mx, __shfl_xor(mx, 32));
        const float mn  = fmaxf(mrun, mx);
        const float fac = __expf(mrun - mn);
        float sum = 0.f;
#pragma unroll
        for (int reg = 0; reg < 16; ++reg) {
            const float pv = __expf(p[reg] - mn);
            p[reg] = pv;
            sum += pv;
        }
        sum += __shfl_xor(sum, 32);
        lrun = lrun * fac + sum;
        mrun = mn;
        o0 *= fac;
        o1 *= fac;

        // ---- P -> bf16 A-frag relayout ----
        unsigned c[8];
#pragma unroll
        for (int i = 0; i < 8; ++i)
            c[i] = (unsigned)f2b(p[2 * i]) | ((unsigned)f2b(p[2 * i + 1]) << 16);
        unsigned w0, w1, w2, w3, w4, w5, w6, w7;
        {
            const unsigned s0w = (unsigned)__shfl_xor((int)c[0], 32);
            const unsigned s1w = (unsigned)__shfl_xor((int)c[1], 32);
            const unsigned s2w = (unsigned)__shfl_xor((int)c[2], 32);
            const unsigned s3w = (unsigned)__shfl_xor((int)c[3], 32);
            w0 = h5 ? s2w : c[0];   w2 = h5 ? c[2] : s0w;
            w1 = h5 ? s3w : c[1];   w3 = h5 ? c[3] : s1w;
            const unsigned s4w = (unsigned)__shfl_xor((int)c[4], 32);
            const unsigned s5w = (unsigned)__shfl_xor((int)c[5], 32);
            const unsigned s6w = (unsigned)__shfl_xor((int)c[6], 32);
            const unsigned s7w = (unsigned)__shfl_xor((int)c[7], 32);
            w4 = h5 ? s6w : c[4];   w6 = h5 ? c[6] : s4w;
            w5 = h5 ? s7w : c[5];   w7 = h5 ? c[7] : s5w;
        }
        u32x4 pa = {w0, w1, w2, w3};
        u32x4 pb = {w4, w5, w6, w7};
        const bf16x8 pf0 = __builtin_bit_cast(bf16x8, pa);
        const bf16x8 pf1 = __builtin_bit_cast(bf16x8, pb);

        // ---- PV: O^T = V^T . P ----
        {
            const unsigned short* vp0 = vtB + (size_t)r        * NT + s0 + h5 * 8;
            const unsigned short* vp1 = vtB + (size_t)(r + 32) * NT + s0 + h5 * 8;
            o0 = MFMA32(LD8(vp0),      pf0, o0);
            o0 = MFMA32(LD8(vp0 + 16), pf1, o0);
            o1 = MFMA32(LD8(vp1),      pf0, o1);
            o1 = MFMA32(LD8(vp1 + 16), pf1, o1);
        }
    }

    // ---- cross-wave combine ----
    __syncthreads();   // all waves done with their sM region
    if (w > 0) {
        float* cb = lds + (size_t)(w - 1) * 2176;
        cb[l]      = mrun;
        cb[64 + l] = lrun;
#pragma unroll
        for (int e = 0; e < 16; ++e) {
            cb[128 + e * 64 + l]        = o0[e];
            cb[128 + 1024 + e * 64 + l] = o1[e];
        }
    }
    __syncthreads();
    if (w == 0) {
#pragma unroll
        for (int wv = 0; wv < 3; ++wv) {
            const float* cb = lds + (size_t)wv * 2176;
            const float mw = cb[l];
            const float lw = cb[64 + l];
            const float mn = fmaxf(mrun, mw);
            const float fa = __expf(mrun - mn);
            const float fb = __expf(mw - mn);
            lrun = lrun * fa + lw * fb;
            mrun = mn;
#pragma unroll
            for (int e = 0; e < 16; ++e) {
                o0[e] = o0[e] * fa + cb[128 + e * 64 + l] * fb;
                o1[e] = o1[e] * fa + cb[128 + 1024 + e * 64 + l] * fb;
            }
        }
        const float inv = 1.f / lrun;
        float* ob = out + (size_t)bb * NT * NH + (size_t)(t0 + r) * NH;
#pragma unroll
        for (int g = 0; g < 4; ++g) {
            float4 v0, v1;
            v0.x = o0[4 * g + 0] * inv; v0.y = o0[4 * g + 1] * inv;
            v0.z = o0[4 * g + 2] * inv; v0.w = o0[4 * g + 3] * inv;
            v1.x = o1[4 * g + 0] * inv; v1.y = o1[4 * g + 1] * inv;
            v1.z = o1[4 * g + 2] * inv; v1.w = o1[4 * g + 3] * inv;
            *reinterpret_cast<float4*>(ob + 8 * g + 4 * h5)      = v0;
            *reinterpret_cast<float4*>(ob + 32 + 8 * g + 4 * h5) = v1;
        }
    }
}

extern "C" void kernel_launch(void* const* d_in, const int* in_sizes, int n_in,
                              void* d_out, int out_size, void* d_ws, size_t ws_size,
                              hipStream_t stream) {
    (void)in_sizes; (void)n_in; (void)out_size; (void)ws_size;
    const float* x  = (const float*)d_in[0];
    const float* Wq = (const float*)d_in[1];
    const float* Wk = (const float*)d_in[2];
    const float* Wv = (const float*)d_in[3];
    const float* Er = (const float*)d_in[4];
    float* outp = (float*)d_out;

    const size_t BTH = (size_t)NB * NT * NH;          // 2,097,152
    unsigned short* qbp = (unsigned short*)d_ws;
    unsigned short* kbp = qbp + BTH;
    unsigned short* vtp = kbp + BTH;
    unsigned short* erp = vtp + BTH;                  // 131,072
    unsigned short* wtp = erp + (size_t)NT * NH;      // 98,304  (total ~13 MB)

    wcast  <<<dim3(48),   dim3(256), 0, stream>>>(Wq, Wk, Wv, wtp);
    er_cast<<<dim3(128),  dim3(256), 0, stream>>>(Er, erp);
    proj_mfma<<<dim3(NB * NT / 32), dim3(64), 0, stream>>>(x, wtp, qbp, kbp, vtp);
    attn_mfma<<<dim3(NB * (NT / 32)), dim3(256), 0, stream>>>(qbp, kbp, vtp, erp, outp);
}

// Round 5
// 248.459 us; speedup vs baseline: 6.1021x; 1.0618x over previous
//
#include <hip/hip_runtime.h>

#define NB 16
#define NT 2048
#define NC 512
#define NH 64
#define SCALE 0.125f

typedef __attribute__((ext_vector_type(8))) short bf16x8;
typedef __attribute__((ext_vector_type(16))) float f32x16;
typedef __attribute__((ext_vector_type(4))) float f32x4;
typedef __attribute__((ext_vector_type(4))) unsigned int u32x4;
typedef __attribute__((ext_vector_type(8))) unsigned short u16x8;

__device__ __forceinline__ unsigned short f2b(float f) {
    unsigned u = __builtin_bit_cast(unsigned, f);
    u = (u + 0x7fffu + ((u >> 16) & 1u)) >> 16;   // RNE
    return (unsigned short)u;
}
__device__ __forceinline__ float b2f(unsigned short s) {
    return __builtin_bit_cast(float, (unsigned)s << 16);
}
#define MFMA32(a, b, c) __builtin_amdgcn_mfma_f32_32x32x16_bf16((a), (b), (c), 0, 0, 0)
#define MFMA16(a, b, c) __builtin_amdgcn_mfma_f32_16x16x32_bf16((a), (b), (c), 0, 0, 0)
#define LD8(p) (*reinterpret_cast<const bf16x8*>(p))

// ---------------- W -> Wt[192][512] bf16 (row = output col, col = k) ----------------
__global__ __launch_bounds__(256) void wcast(
    const float* __restrict__ Wq, const float* __restrict__ Wk,
    const float* __restrict__ Wv, unsigned short* __restrict__ wt)
{
    const int tid = blockIdx.x * 256 + threadIdx.x;   // 0..12287
    const int ng = tid >> 6;                           // 0..191
    const int k8 = tid & 63;                           // 0..63
    const float* W = (ng < 64) ? Wq : (ng < 128 ? Wk : Wv);
    const int n = ng & 63;
    u16x8 o;
#pragma unroll
    for (int i = 0; i < 8; ++i) o[i] = f2b(W[(k8 * 8 + i) * NH + n]);
    *reinterpret_cast<u16x8*>(wt + (size_t)ng * NC + k8 * 8) = o;
}

// ---------------- Er f32 -> bf16 ----------------
__global__ __launch_bounds__(256) void er_cast(const float* __restrict__ er,
                                               unsigned short* __restrict__ erb)
{
    const int i = (blockIdx.x * 256 + threadIdx.x) * 4;
    float4 v = *reinterpret_cast<const float4*>(er + i);
    ushort4 o = make_ushort4(f2b(v.x), f2b(v.y), f2b(v.z), f2b(v.w));
    *reinterpret_cast<ushort4*>(erb + i) = o;
}

// ---------------- MFMA projection: 16x16x32, 1 wave / 16 rows, 2048 waves ----------------
__global__ __launch_bounds__(64, 2) void proj_mfma(
    const float* __restrict__ x, const unsigned short* __restrict__ wt,
    unsigned short* __restrict__ qb, unsigned short* __restrict__ kb,
    unsigned short* __restrict__ vtg)
{
    const int l  = threadIdx.x;
    const int cl = l & 15;      // A row / B col / C col
    const int kq = l >> 4;      // k-chunk selector (K=32: k = kq*8 + j)
    const size_t t0 = (size_t)blockIdx.x * 16;

    f32x4 acc[12];
#pragma unroll
    for (int g = 0; g < 12; ++g) acc[g] = (f32x4){0.f, 0.f, 0.f, 0.f};

    const float* xr = x + (t0 + cl) * NC + kq * 8;
    const unsigned short* wrow = wt + (size_t)cl * NC + kq * 8;

    // x software pipeline (one k-step ahead)
    float4 xa = *reinterpret_cast<const float4*>(xr);
    float4 xb = *reinterpret_cast<const float4*>(xr + 4);

#pragma unroll
    for (int s = 0; s < 16; ++s) {
        float4 na = xa, nb = xb;
        if (s < 15) {
            na = *reinterpret_cast<const float4*>(xr + (s + 1) * 32);
            nb = *reinterpret_cast<const float4*>(xr + (s + 1) * 32 + 4);
        }
        u32x4 aw;
        aw[0] = (unsigned)f2b(xa.x) | ((unsigned)f2b(xa.y) << 16);
        aw[1] = (unsigned)f2b(xa.z) | ((unsigned)f2b(xa.w) << 16);
        aw[2] = (unsigned)f2b(xb.x) | ((unsigned)f2b(xb.y) << 16);
        aw[3] = (unsigned)f2b(xb.z) | ((unsigned)f2b(xb.w) << 16);
        const bf16x8 af = __builtin_bit_cast(bf16x8, aw);
        const unsigned short* wp = wrow + s * 32;
#pragma unroll
        for (int g = 0; g < 12; ++g)
            acc[g] = MFMA16(af, LD8(wp + (size_t)g * 16 * NC), acc[g]);
        xa = na; xb = nb;
    }

    // q,k row-major stores: C layout col=cl, row=kq*4+i
#pragma unroll
    for (int i = 0; i < 4; ++i) {
        const size_t row = t0 + kq * 4 + i;
#pragma unroll
        for (int g = 0; g < 4; ++g) {
            qb[row * NH + g * 16 + cl] = f2b(acc[g][i]);
            kb[row * NH + g * 16 + cl] = f2b(acc[g + 4][i]);
        }
    }
    // V^T stores: h = g*16+cl, t = t0+kq*4+i (4 t packed per 8B store)
    const size_t bidx = t0 >> 11;
    const int tloc = (int)(t0 & 2047);
#pragma unroll
    for (int g = 0; g < 4; ++g) {
        ushort4 pv;
        pv.x = f2b(acc[g + 8][0]); pv.y = f2b(acc[g + 8][1]);
        pv.z = f2b(acc[g + 8][2]); pv.w = f2b(acc[g + 8][3]);
        *reinterpret_cast<ushort4*>(vtg + (bidx * NH + g * 16 + cl) * NT + tloc + kq * 4) = pv;
    }
}

// ---------------- MFMA rel-attention, 4 waves split-K, heavy-first dispatch ----------------
// score(t,s) = qk*SCALE + { diag[t] if t==s ; 0 if t==s+1 ; q[s+1].Er[t-s-2] if t>=s+2 }
__global__ __launch_bounds__(256, 2) void attn_mfma(
    const unsigned short* __restrict__ qb, const unsigned short* __restrict__ kb,
    const unsigned short* __restrict__ vt, const unsigned short* __restrict__ erb,
    float* __restrict__ out)
{
    __shared__ float lds[4 * 2048];   // 32 KB: per-wave sM during loop; combine buffer after

    const int tid = threadIdx.x;
    const int l  = tid & 63;
    const int w  = tid >> 6;
    const int r  = l & 31;
    const int h5 = (l >> 5) & 1;

    // heavy-first: first 16 blocks are tq=63 across all batches
    const int lin = blockIdx.x;
    const int bb  = lin & 15;
    const int tq  = 63 - (lin >> 4);
    const int t0  = tq * 32;

    const unsigned short* qB  = qb + (size_t)bb * NT * NH;
    const unsigned short* kB  = kb + (size_t)bb * NT * NH;
    const unsigned short* vtB = vt + (size_t)bb * NH * NT;

    float* sM = lds + w * 2048;

    // Q fragments (B-operand: lane holds q-row r)
    const unsigned short* qp = qB + (size_t)(t0 + r) * NH + h5 * 8;
    bf16x8 qf[4];
#pragma unroll
    for (int ks = 0; ks < 4; ++ks) qf[ks] = LD8(qp + ks * 16);

    // diag[r] = q[t0+r] . Er[T-1]  (vectorized)
    float diag = 0.f;
    {
        const unsigned short* qrow = qB + (size_t)(t0 + r) * NH;
        const unsigned short* el   = erb + (size_t)(NT - 1) * NH;
#pragma unroll
        for (int h8 = 0; h8 < 8; ++h8) {
            ushort4 qa = *reinterpret_cast<const ushort4*>(qrow + h8 * 8);
            ushort4 qc = *reinterpret_cast<const ushort4*>(qrow + h8 * 8 + 4);
            ushort4 ea = *reinterpret_cast<const ushort4*>(el + h8 * 8);
            ushort4 ec = *reinterpret_cast<const ushort4*>(el + h8 * 8 + 4);
            diag += b2f(qa.x) * b2f(ea.x) + b2f(qa.y) * b2f(ea.y)
                  + b2f(qa.z) * b2f(ea.z) + b2f(qa.w) * b2f(ea.w)
                  + b2f(qc.x) * b2f(ec.x) + b2f(qc.y) * b2f(ec.y)
                  + b2f(qc.z) * b2f(ec.z) + b2f(qc.w) * b2f(ec.w);
        }
    }

    float mrun = -1e30f, lrun = 0.f;
    f32x16 o0 = {}, o1 = {};

    const int ntiles = tq + 1;

    // cross-tile K prefetch
    bf16x8 kcur[4], knxt[4];
    if (w < ntiles) {
        const unsigned short* kp = kB + (size_t)(w * 32 + r) * NH + h5 * 8;
#pragma unroll
        for (int ks = 0; ks < 4; ++ks) kcur[ks] = LD8(kp + ks * 16);
    }

    for (int it = w; it < ntiles; it += 4) {
        const int s0 = it * 32;
        const int D0 = t0 - s0;

        // prefetch next tile's K
        const int itn = it + 4;
        if (itn < ntiles) {
            const unsigned short* kp = kB + (size_t)(itn * 32 + r) * NH + h5 * 8;
#pragma unroll
            for (int ks = 0; ks < 4; ++ks) knxt[ks] = LD8(kp + ks * 16);
        }

        // issue rel operands early
        int arow = s0 + 1 + r; if (arow > NT - 1) arow = NT - 1;   // clamped rows unused
        int e0 = D0 - 33 + r;  const int e0c = e0 < 0 ? 0 : e0;    // clamped rows unused
        int e1 = e0 + 32;      const int e1c = e1 < 0 ? 0 : e1;
        const unsigned short* ap  = qB  + (size_t)arow * NH + h5 * 8;
        const unsigned short* ep0 = erb + (size_t)e0c  * NH + h5 * 8;
        const unsigned short* ep1 = erb + (size_t)e1c  * NH + h5 * 8;
        bf16x8 afr[4], ef0[4], ef1[4];
#pragma unroll
        for (int ks = 0; ks < 4; ++ks) {
            afr[ks] = LD8(ap + ks * 16);
            ef0[ks] = LD8(ep0 + ks * 16);
            ef1[ks] = LD8(ep1 + ks * 16);
        }

        // ---- S^T = K . Q^T (kcur already resident) ----
        f32x16 st = {};
#pragma unroll
        for (int ks = 0; ks < 4; ++ks) st = MFMA32(kcur[ks], qf[ks], st);

        // ---- rel GEMM ----
        f32x16 mA = {}, mB = {};
#pragma unroll
        for (int ks = 0; ks < 4; ++ks) {
            mA = MFMA32(afr[ks], ef0[ks], mA);
            mB = MFMA32(afr[ks], ef1[ks], mB);
        }

        // issue V loads early (consumed after softmax)
        const unsigned short* vp0 = vtB + (size_t)r        * NT + s0 + h5 * 8;
        const unsigned short* vp1 = vtB + (size_t)(r + 32) * NT + s0 + h5 * 8;
        const bf16x8 vf0a = LD8(vp0), vf0b = LD8(vp0 + 16);
        const bf16x8 vf1a = LD8(vp1), vf1b = LD8(vp1 + 16);

#pragma unroll
        for (int reg = 0; reg < 16; ++reg) {
            const int da = (reg & 3) + 8 * (reg >> 2) + 4 * h5;
            sM[da * 64 + r]      = mA[reg];
            sM[da * 64 + r + 32] = mB[reg];
        }

        // ---- scores + online softmax (row r lane-local) ----
        float p[16];
        float mx = -1e30f;
#pragma unroll
        for (int reg = 0; reg < 16; ++reg) {
            const int dc = (reg & 3) + 8 * (reg >> 2) + 4 * h5;
            const int d  = r - dc + D0;
            float sc = st[reg] * SCALE;
            const float Mv = sM[dc * 64 + (r - dc + 31)];
            sc += (d >= 2) ? Mv : ((d == 0) ? diag : 0.0f);
            sc = (d < 0) ? -1e30f : sc;
            p[reg] = sc;
            mx = fmaxf(mx, sc);
        }
        mx = fmaxf(mx, __shfl_xor(mx, 32));
        const float mn  = fmaxf(mrun, mx);
        const float fac = __expf(mrun - mn);
        float sum = 0.f;
#pragma unroll
        for (int reg = 0; reg < 16; ++reg) {
            const float pv = __expf(p[reg] - mn);
            p[reg] = pv;
            sum += pv;
        }
        sum += __shfl_xor(sum, 32);
        lrun = lrun * fac + sum;
        mrun = mn;
        o0 *= fac;
        o1 *= fac;

        // ---- P -> bf16 A-frag relayout ----
        unsigned c[8];
#pragma unroll
        for (int i = 0; i < 8; ++i)
            c[i] = (unsigned)f2b(p[2 * i]) | ((unsigned)f2b(p[2 * i + 1]) << 16);
        unsigned w0, w1, w2, w3, w4, w5, w6, w7;
        {
            const unsigned s0w = (unsigned)__shfl_xor((int)c[0], 32);
            const unsigned s1w = (unsigned)__shfl_xor((int)c[1], 32);
            const unsigned s2w = (unsigned)__shfl_xor((int)c[2], 32);
            const unsigned s3w = (unsigned)__shfl_xor((int)c[3], 32);
            w0 = h5 ? s2w : c[0];   w2 = h5 ? c[2] : s0w;
            w1 = h5 ? s3w : c[1];   w3 = h5 ? c[3] : s1w;
            const unsigned s4w = (unsigned)__shfl_xor((int)c[4], 32);
            const unsigned s5w = (unsigned)__shfl_xor((int)c[5], 32);
            const unsigned s6w = (unsigned)__shfl_xor((int)c[6], 32);
            const unsigned s7w = (unsigned)__shfl_xor((int)c[7], 32);
            w4 = h5 ? s6w : c[4];   w6 = h5 ? c[6] : s4w;
            w5 = h5 ? s7w : c[5];   w7 = h5 ? c[7] : s5w;
        }
        u32x4 pa = {w0, w1, w2, w3};
        u32x4 pb = {w4, w5, w6, w7};
        const bf16x8 pf0 = __builtin_bit_cast(bf16x8, pa);
        const bf16x8 pf1 = __builtin_bit_cast(bf16x8, pb);

        // ---- PV: O^T = V^T . P ----
        o0 = MFMA32(vf0a, pf0, o0);
        o0 = MFMA32(vf0b, pf1, o0);
        o1 = MFMA32(vf1a, pf0, o1);
        o1 = MFMA32(vf1b, pf1, o1);

#pragma unroll
        for (int ks = 0; ks < 4; ++ks) kcur[ks] = knxt[ks];
    }

    // ---- cross-wave combine ----
    __syncthreads();
    if (w > 0) {
        float* cb = lds + (size_t)(w - 1) * 2176;
        cb[l]      = mrun;
        cb[64 + l] = lrun;
#pragma unroll
        for (int e = 0; e < 16; ++e) {
            cb[128 + e * 64 + l]        = o0[e];
            cb[128 + 1024 + e * 64 + l] = o1[e];
        }
    }
    __syncthreads();
    if (w == 0) {
#pragma unroll
        for (int wv = 0; wv < 3; ++wv) {
            const float* cb = lds + (size_t)wv * 2176;
            const float mw = cb[l];
            const float lw = cb[64 + l];
            const float mn = fmaxf(mrun, mw);
            const float fa = __expf(mrun - mn);
            const float fb = __expf(mw - mn);
            lrun = lrun * fa + lw * fb;
            mrun = mn;
#pragma unroll
            for (int e = 0; e < 16; ++e) {
                o0[e] = o0[e] * fa + cb[128 + e * 64 + l] * fb;
                o1[e] = o1[e] * fa + cb[128 + 1024 + e * 64 + l] * fb;
            }
        }
        const float inv = 1.f / lrun;
        float* ob = out + (size_t)bb * NT * NH + (size_t)(t0 + r) * NH;
#pragma unroll
        for (int g = 0; g < 4; ++g) {
            float4 v0, v1;
            v0.x = o0[4 * g + 0] * inv; v0.y = o0[4 * g + 1] * inv;
            v0.z = o0[4 * g + 2] * inv; v0.w = o0[4 * g + 3] * inv;
            v1.x = o1[4 * g + 0] * inv; v1.y = o1[4 * g + 1] * inv;
            v1.z = o1[4 * g + 2] * inv; v1.w = o1[4 * g + 3] * inv;
            *reinterpret_cast<float4*>(ob + 8 * g + 4 * h5)      = v0;
            *reinterpret_cast<float4*>(ob + 32 + 8 * g + 4 * h5) = v1;
        }
    }
}

extern "C" void kernel_launch(void* const* d_in, const int* in_sizes, int n_in,
                              void* d_out, int out_size, void* d_ws, size_t ws_size,
                              hipStream_t stream) {
    (void)in_sizes; (void)n_in; (void)out_size; (void)ws_size;
    const float* x  = (const float*)d_in[0];
    const float* Wq = (const float*)d_in[1];
    const float* Wk = (const float*)d_in[2];
    const float* Wv = (const float*)d_in[3];
    const float* Er = (const float*)d_in[4];
    float* outp = (float*)d_out;

    const size_t BTH = (size_t)NB * NT * NH;          // 2,097,152
    unsigned short* qbp = (unsigned short*)d_ws;
    unsigned short* kbp = qbp + BTH;
    unsigned short* vtp = kbp + BTH;
    unsigned short* erp = vtp + BTH;                  // 131,072
    unsigned short* wtp = erp + (size_t)NT * NH;      // 98,304  (total ~13 MB)

    wcast  <<<dim3(48),  dim3(256), 0, stream>>>(Wq, Wk, Wv, wtp);
    er_cast<<<dim3(128), dim3(256), 0, stream>>>(Er, erp);
    proj_mfma<<<dim3(NB * NT / 16), dim3(64), 0, stream>>>(x, wtp, qbp, kbp, vtp);
    attn_mfma<<<dim3(NB * (NT / 32)), dim3(256), 0, stream>>>(qbp, kbp, vtp, erp, outp);
}

// Round 6
// 207.223 us; speedup vs baseline: 7.3163x; 1.1990x over previous
//
#include <hip/hip_runtime.h>

#define NB 16
#define NT 2048
#define NC 512
#define NH 64
#define SCALE 0.125f

typedef __attribute__((ext_vector_type(8))) short bf16x8;
typedef __attribute__((ext_vector_type(16))) float f32x16;
typedef __attribute__((ext_vector_type(4))) float f32x4;
typedef __attribute__((ext_vector_type(4))) unsigned int u32x4;
typedef __attribute__((ext_vector_type(8))) unsigned short u16x8;

__device__ __forceinline__ unsigned short f2b(float f) {
    unsigned u = __builtin_bit_cast(unsigned, f);
    u = (u + 0x7fffu + ((u >> 16) & 1u)) >> 16;   // RNE
    return (unsigned short)u;
}
__device__ __forceinline__ float b2f(unsigned short s) {
    return __builtin_bit_cast(float, (unsigned)s << 16);
}
__device__ __forceinline__ unsigned cvt_pk_bf16(float lo, float hi) {
    unsigned r;
    asm("v_cvt_pk_bf16_f32 %0, %1, %2" : "=v"(r) : "v"(lo), "v"(hi));
    return r;
}
#define MFMA32(a, b, c) __builtin_amdgcn_mfma_f32_32x32x16_bf16((a), (b), (c), 0, 0, 0)
#define MFMA16(a, b, c) __builtin_amdgcn_mfma_f32_16x16x32_bf16((a), (b), (c), 0, 0, 0)
#define LD8(p) (*reinterpret_cast<const bf16x8*>(p))

// ---------------- W -> wfrag[kstep][g][lane][8] bf16 (MFMA B-fragment order) ----------------
// element: n = g*16 + (lane&15); k = kstep*32 + (lane>>4)*8 + j
__global__ __launch_bounds__(256) void wcast(
    const float* __restrict__ Wq, const float* __restrict__ Wk,
    const float* __restrict__ Wv, unsigned short* __restrict__ wfrag)
{
    const int idx = blockIdx.x * 256 + threadIdx.x;   // 0..12287
    const int kstep = idx / 768;
    const int rem   = idx % 768;
    const int g = rem >> 6;
    const int l = rem & 63;
    const int n  = g * 16 + (l & 15);
    const int kb = kstep * 32 + ((l >> 4) << 3);
    const float* W = (n < 64) ? Wq : (n < 128 ? Wk : Wv);
    const int col = n & 63;
    u16x8 o;
#pragma unroll
    for (int j = 0; j < 8; ++j) o[j] = f2b(W[(size_t)(kb + j) * NH + col]);
    *reinterpret_cast<u16x8*>(wfrag + (size_t)idx * 8) = o;
}

// ---------------- Er f32 -> bf16 ----------------
__global__ __launch_bounds__(256) void er_cast(const float* __restrict__ er,
                                               unsigned short* __restrict__ erb)
{
    const int i = (blockIdx.x * 256 + threadIdx.x) * 4;
    float4 v = *reinterpret_cast<const float4*>(er + i);
    ushort4 o = make_ushort4(f2b(v.x), f2b(v.y), f2b(v.z), f2b(v.w));
    *reinterpret_cast<ushort4*>(erb + i) = o;
}

// ---------------- proj GEMM: 4 waves, M=64/block, W LDS-staged double-buffered ----------------
__global__ __launch_bounds__(256, 2) void proj_mfma(
    const float* __restrict__ x, const unsigned short* __restrict__ wfrag,
    unsigned short* __restrict__ qb, unsigned short* __restrict__ kb,
    unsigned short* __restrict__ vtg)
{
    __shared__ unsigned short wsh[2][6144];   // 2 x 12 KB W chunk (one K=32 step, all 192 n)

    const int tid = threadIdx.x;
    const int w = tid >> 6;
    const int l = tid & 63;
    const int cl = l & 15;      // matrix row (t) / output col (n) fragment index
    const int kq = l >> 4;      // k-subchunk 0..3

    const size_t t0w = (size_t)blockIdx.x * 64 + w * 16;   // this wave's 16 rows
    const float* xr = x + (t0w + cl) * NC + kq * 8;

    f32x4 acc[12];
#pragma unroll
    for (int g = 0; g < 12; ++g) acc[g] = (f32x4){0.f, 0.f, 0.f, 0.f};

    // stage kstep 0 into buf 0
#pragma unroll
    for (int j = 0; j < 3; ++j) {
        const int c = w * 3 + j;
        const unsigned short* gsrc = wfrag + ((size_t)(0 * 12 + c) * 64 + l) * 8;
        __builtin_amdgcn_global_load_lds(
            (const __attribute__((address_space(1))) void*)gsrc,
            (__attribute__((address_space(3))) void*)&wsh[0][c * 512], 16, 0, 0);
    }
    // x prefetch for kstep 0
    float4 xa = *reinterpret_cast<const float4*>(xr);
    float4 xb = *reinterpret_cast<const float4*>(xr + 4);

    for (int k = 0; k < 16; ++k) {
        const int buf = k & 1;
        asm volatile("s_waitcnt vmcnt(0)" ::: "memory");
        __syncthreads();
        float4 na = xa, nb = xb;
        if (k < 15) {
            // stage next W chunk into other buffer
#pragma unroll
            for (int j = 0; j < 3; ++j) {
                const int c = w * 3 + j;
                const unsigned short* gsrc = wfrag + ((size_t)((k + 1) * 12 + c) * 64 + l) * 8;
                __builtin_amdgcn_global_load_lds(
                    (const __attribute__((address_space(1))) void*)gsrc,
                    (__attribute__((address_space(3))) void*)&wsh[buf ^ 1][c * 512], 16, 0, 0);
            }
            na = *reinterpret_cast<const float4*>(xr + (k + 1) * 32);
            nb = *reinterpret_cast<const float4*>(xr + (k + 1) * 32 + 4);
        }
        u32x4 aw;
        aw[0] = cvt_pk_bf16(xa.x, xa.y);
        aw[1] = cvt_pk_bf16(xa.z, xa.w);
        aw[2] = cvt_pk_bf16(xb.x, xb.y);
        aw[3] = cvt_pk_bf16(xb.z, xb.w);
        const bf16x8 af = __builtin_bit_cast(bf16x8, aw);
#pragma unroll
        for (int g = 0; g < 12; ++g) {
            const bf16x8 bf = *reinterpret_cast<const bf16x8*>(&wsh[buf][g * 512 + l * 8]);
            acc[g] = MFMA16(af, bf, acc[g]);
        }
        xa = na; xb = nb;
    }

    // q,k row-major stores: C layout col=cl (n), row=kq*4+i (t-local)
#pragma unroll
    for (int i = 0; i < 4; ++i) {
        const size_t row = t0w + kq * 4 + i;
#pragma unroll
        for (int g = 0; g < 4; ++g) {
            qb[row * NH + g * 16 + cl] = f2b(acc[g][i]);
            kb[row * NH + g * 16 + cl] = f2b(acc[g + 4][i]);
        }
    }
    // V^T stores: h = g*16+cl, t = t0w+kq*4+i (4 t packed per 8B store)
    const size_t rowb = t0w + kq * 4;
    const size_t bidx = rowb >> 11;
    const int tloc = (int)(rowb & 2047);
#pragma unroll
    for (int g = 0; g < 4; ++g) {
        unsigned u0 = cvt_pk_bf16(acc[g + 8][0], acc[g + 8][1]);
        unsigned u1 = cvt_pk_bf16(acc[g + 8][2], acc[g + 8][3]);
        uint2 pv = make_uint2(u0, u1);
        *reinterpret_cast<uint2*>(vtg + (bidx * NH + g * 16 + cl) * NT + tloc) = pv;
    }
}

// ---------------- MFMA rel-attention, 4 waves split-K, heavy-first dispatch ----------------
// score(t,s) = qk*SCALE + { diag[t] if t==s ; 0 if t==s+1 ; q[s+1].Er[t-s-2] if t>=s+2 }
__global__ __launch_bounds__(256, 2) void attn_mfma(
    const unsigned short* __restrict__ qb, const unsigned short* __restrict__ kb,
    const unsigned short* __restrict__ vt, const unsigned short* __restrict__ erb,
    float* __restrict__ out)
{
    __shared__ float lds[4 * 2048];   // 32 KB: per-wave sM during loop; combine buffer after

    const int tid = threadIdx.x;
    const int l  = tid & 63;
    const int w  = tid >> 6;
    const int r  = l & 31;
    const int h5 = (l >> 5) & 1;

    // heavy-first: first 16 blocks are tq=63 across all batches
    const int lin = blockIdx.x;
    const int bb  = lin & 15;
    const int tq  = 63 - (lin >> 4);
    const int t0  = tq * 32;

    const unsigned short* qB  = qb + (size_t)bb * NT * NH;
    const unsigned short* kB  = kb + (size_t)bb * NT * NH;
    const unsigned short* vtB = vt + (size_t)bb * NH * NT;

    float* sM = lds + w * 2048;

    // Q fragments (B-operand: lane holds q-row r)
    const unsigned short* qp = qB + (size_t)(t0 + r) * NH + h5 * 8;
    bf16x8 qf[4];
#pragma unroll
    for (int ks = 0; ks < 4; ++ks) qf[ks] = LD8(qp + ks * 16);

    // diag[r] = q[t0+r] . Er[T-1]  (vectorized)
    float diag = 0.f;
    {
        const unsigned short* qrow = qB + (size_t)(t0 + r) * NH;
        const unsigned short* el   = erb + (size_t)(NT - 1) * NH;
#pragma unroll
        for (int h8 = 0; h8 < 8; ++h8) {
            ushort4 qa = *reinterpret_cast<const ushort4*>(qrow + h8 * 8);
            ushort4 qc = *reinterpret_cast<const ushort4*>(qrow + h8 * 8 + 4);
            ushort4 ea = *reinterpret_cast<const ushort4*>(el + h8 * 8);
            ushort4 ec = *reinterpret_cast<const ushort4*>(el + h8 * 8 + 4);
            diag += b2f(qa.x) * b2f(ea.x) + b2f(qa.y) * b2f(ea.y)
                  + b2f(qa.z) * b2f(ea.z) + b2f(qa.w) * b2f(ea.w)
                  + b2f(qc.x) * b2f(ec.x) + b2f(qc.y) * b2f(ec.y)
                  + b2f(qc.z) * b2f(ec.z) + b2f(qc.w) * b2f(ec.w);
        }
    }

    float mrun = -1e30f, lrun = 0.f;
    f32x16 o0 = {}, o1 = {};

    const int ntiles = tq + 1;

    // cross-tile K prefetch
    bf16x8 kcur[4], knxt[4];
    if (w < ntiles) {
        const unsigned short* kp = kB + (size_t)(w * 32 + r) * NH + h5 * 8;
#pragma unroll
        for (int ks = 0; ks < 4; ++ks) kcur[ks] = LD8(kp + ks * 16);
    }

    for (int it = w; it < ntiles; it += 4) {
        const int s0 = it * 32;
        const int D0 = t0 - s0;

        // prefetch next tile's K
        const int itn = it + 4;
        if (itn < ntiles) {
            const unsigned short* kp = kB + (size_t)(itn * 32 + r) * NH + h5 * 8;
#pragma unroll
            for (int ks = 0; ks < 4; ++ks) knxt[ks] = LD8(kp + ks * 16);
        }

        // issue rel operands early
        int arow = s0 + 1 + r; if (arow > NT - 1) arow = NT - 1;   // clamped rows unused
        int e0 = D0 - 33 + r;  const int e0c = e0 < 0 ? 0 : e0;    // clamped rows unused
        int e1 = e0 + 32;      const int e1c = e1 < 0 ? 0 : e1;
        const unsigned short* ap  = qB  + (size_t)arow * NH + h5 * 8;
        const unsigned short* ep0 = erb + (size_t)e0c  * NH + h5 * 8;
        const unsigned short* ep1 = erb + (size_t)e1c  * NH + h5 * 8;
        bf16x8 afr[4], ef0[4], ef1[4];
#pragma unroll
        for (int ks = 0; ks < 4; ++ks) {
            afr[ks] = LD8(ap + ks * 16);
            ef0[ks] = LD8(ep0 + ks * 16);
            ef1[ks] = LD8(ep1 + ks * 16);
        }

        // ---- S^T = K . Q^T and rel GEMM (MFMA cluster, prio-boosted) ----
        __builtin_amdgcn_s_setprio(1);
        f32x16 st = {};
#pragma unroll
        for (int ks = 0; ks < 4; ++ks) st = MFMA32(kcur[ks], qf[ks], st);
        f32x16 mA = {}, mB = {};
#pragma unroll
        for (int ks = 0; ks < 4; ++ks) {
            mA = MFMA32(afr[ks], ef0[ks], mA);
            mB = MFMA32(afr[ks], ef1[ks], mB);
        }
        __builtin_amdgcn_s_setprio(0);

        // issue V loads early (consumed after softmax)
        const unsigned short* vp0 = vtB + (size_t)r        * NT + s0 + h5 * 8;
        const unsigned short* vp1 = vtB + (size_t)(r + 32) * NT + s0 + h5 * 8;
        const bf16x8 vf0a = LD8(vp0), vf0b = LD8(vp0 + 16);
        const bf16x8 vf1a = LD8(vp1), vf1b = LD8(vp1 + 16);

#pragma unroll
        for (int reg = 0; reg < 16; ++reg) {
            const int da = (reg & 3) + 8 * (reg >> 2) + 4 * h5;
            sM[da * 64 + r]      = mA[reg];
            sM[da * 64 + r + 32] = mB[reg];
        }

        // ---- scores + online softmax (row r lane-local) ----
        float p[16];
        float mx = -1e30f;
#pragma unroll
        for (int reg = 0; reg < 16; ++reg) {
            const int dc = (reg & 3) + 8 * (reg >> 2) + 4 * h5;
            const int d  = r - dc + D0;
            float sc = st[reg] * SCALE;
            const float Mv = sM[dc * 64 + (r - dc + 31)];
            sc += (d >= 2) ? Mv : ((d == 0) ? diag : 0.0f);
            sc = (d < 0) ? -1e30f : sc;
            p[reg] = sc;
            mx = fmaxf(mx, sc);
        }
        mx = fmaxf(mx, __shfl_xor(mx, 32));
        const float mn  = fmaxf(mrun, mx);
        const float fac = __expf(mrun - mn);
        float sum = 0.f;
#pragma unroll
        for (int reg = 0; reg < 16; ++reg) {
            const float pv = __expf(p[reg] - mn);
            p[reg] = pv;
            sum += pv;
        }
        sum += __shfl_xor(sum, 32);
        lrun = lrun * fac + sum;
        mrun = mn;
        o0 *= fac;
        o1 *= fac;

        // ---- P -> bf16 A-frag relayout (cvt_pk + cross-half shfl) ----
        unsigned c[8];
#pragma unroll
        for (int i = 0; i < 8; ++i)
            c[i] = cvt_pk_bf16(p[2 * i], p[2 * i + 1]);
        unsigned w0, w1, w2, w3, w4, w5, w6, w7;
        {
            const unsigned s0w = (unsigned)__shfl_xor((int)c[0], 32);
            const unsigned s1w = (unsigned)__shfl_xor((int)c[1], 32);
            const unsigned s2w = (unsigned)__shfl_xor((int)c[2], 32);
            const unsigned s3w = (unsigned)__shfl_xor((int)c[3], 32);
            w0 = h5 ? s2w : c[0];   w2 = h5 ? c[2] : s0w;
            w1 = h5 ? s3w : c[1];   w3 = h5 ? c[3] : s1w;
            const unsigned s4w = (unsigned)__shfl_xor((int)c[4], 32);
            const unsigned s5w = (unsigned)__shfl_xor((int)c[5], 32);
            const unsigned s6w = (unsigned)__shfl_xor((int)c[6], 32);
            const unsigned s7w = (unsigned)__shfl_xor((int)c[7], 32);
            w4 = h5 ? s6w : c[4];   w6 = h5 ? c[6] : s4w;
            w5 = h5 ? s7w : c[5];   w7 = h5 ? c[7] : s5w;
        }
        u32x4 pa = {w0, w1, w2, w3};
        u32x4 pb = {w4, w5, w6, w7};
        const bf16x8 pf0 = __builtin_bit_cast(bf16x8, pa);
        const bf16x8 pf1 = __builtin_bit_cast(bf16x8, pb);

        // ---- PV: O^T = V^T . P ----
        __builtin_amdgcn_s_setprio(1);
        o0 = MFMA32(vf0a, pf0, o0);
        o0 = MFMA32(vf0b, pf1, o0);
        o1 = MFMA32(vf1a, pf0, o1);
        o1 = MFMA32(vf1b, pf1, o1);
        __builtin_amdgcn_s_setprio(0);

#pragma unroll
        for (int ks = 0; ks < 4; ++ks) kcur[ks] = knxt[ks];
    }

    // ---- cross-wave combine ----
    __syncthreads();
    if (w > 0) {
        float* cb = lds + (size_t)(w - 1) * 2176;
        cb[l]      = mrun;
        cb[64 + l] = lrun;
#pragma unroll
        for (int e = 0; e < 16; ++e) {
            cb[128 + e * 64 + l]        = o0[e];
            cb[128 + 1024 + e * 64 + l] = o1[e];
        }
    }
    __syncthreads();
    if (w == 0) {
#pragma unroll
        for (int wv = 0; wv < 3; ++wv) {
            const float* cb = lds + (size_t)wv * 2176;
            const float mw = cb[l];
            const float lw = cb[64 + l];
            const float mn = fmaxf(mrun, mw);
            const float fa = __expf(mrun - mn);
            const float fb = __expf(mw - mn);
            lrun = lrun * fa + lw * fb;
            mrun = mn;
#pragma unroll
            for (int e = 0; e < 16; ++e) {
                o0[e] = o0[e] * fa + cb[128 + e * 64 + l] * fb;
                o1[e] = o1[e] * fa + cb[128 + 1024 + e * 64 + l] * fb;
            }
        }
        const float inv = 1.f / lrun;
        float* ob = out + (size_t)bb * NT * NH + (size_t)(t0 + r) * NH;
#pragma unroll
        for (int g = 0; g < 4; ++g) {
            float4 v0, v1;
            v0.x = o0[4 * g + 0] * inv; v0.y = o0[4 * g + 1] * inv;
            v0.z = o0[4 * g + 2] * inv; v0.w = o0[4 * g + 3] * inv;
            v1.x = o1[4 * g + 0] * inv; v1.y = o1[4 * g + 1] * inv;
            v1.z = o1[4 * g + 2] * inv; v1.w = o1[4 * g + 3] * inv;
            *reinterpret_cast<float4*>(ob + 8 * g + 4 * h5)      = v0;
            *reinterpret_cast<float4*>(ob + 32 + 8 * g + 4 * h5) = v1;
        }
    }
}

extern "C" void kernel_launch(void* const* d_in, const int* in_sizes, int n_in,
                              void* d_out, int out_size, void* d_ws, size_t ws_size,
                              hipStream_t stream) {
    (void)in_sizes; (void)n_in; (void)out_size; (void)ws_size;
    const float* x  = (const float*)d_in[0];
    const float* Wq = (const float*)d_in[1];
    const float* Wk = (const float*)d_in[2];
    const float* Wv = (const float*)d_in[3];
    const float* Er = (const float*)d_in[4];
    float* outp = (float*)d_out;

    const size_t BTH = (size_t)NB * NT * NH;          // 2,097,152
    unsigned short* qbp = (unsigned short*)d_ws;
    unsigned short* kbp = qbp + BTH;
    unsigned short* vtp = kbp + BTH;
    unsigned short* erp = vtp + BTH;                  // 131,072
    unsigned short* wfp = erp + (size_t)NT * NH;      // 98,304  (total ~13 MB)

    wcast  <<<dim3(48),  dim3(256), 0, stream>>>(Wq, Wk, Wv, wfp);
    er_cast<<<dim3(128), dim3(256), 0, stream>>>(Er, erp);
    proj_mfma<<<dim3(NB * NT / 64), dim3(256), 0, stream>>>(x, wfp, qbp, kbp, vtp);
    attn_mfma<<<dim3(NB * (NT / 32)), dim3(256), 0, stream>>>(qbp, kbp, vtp, erp, outp);
}